// Round 10
// baseline (564.145 us; speedup 1.0000x reference)
//
#include <hip/hip_runtime.h>
#include <cstdint>
#include <cstddef>

#define NEG_SLOPE 0.2f

typedef _Float16 f16x8 __attribute__((ext_vector_type(8)));
typedef float f32x4v __attribute__((ext_vector_type(4)));

__device__ __forceinline__ unsigned enc_f(float f) {
  unsigned u = __float_as_uint(f);
  return (u & 0x80000000u) ? ~u : (u | 0x80000000u);
}
__device__ __forceinline__ float dec_f(unsigned u) {
  return (u & 0x80000000u) ? __uint_as_float(u ^ 0x80000000u) : __uint_as_float(~u);
}

#define AST 136
#define ABYTES (64 * AST * 2)                 // 17408: A tile (fp16), aliased by fp16 h stage
#define SMEM_BYTES (ABYTES + 4 * 64 * 2 * 4)  // + 2KB cross-wave s/d partials = 19456 (8 blk/CU = 32-wave cap)

// -------- FUSED: count_rank (atomic floor) || prep (bounds + W->fp16 transposes) ----------------
// Both parts LDS-free -> no occupancy interference with the returning-atomic pipeline
// (r1/r3 failures were LDS-heavy co-residents). counts[] zeroed by hipMemsetAsync beforehand.
__global__ void k_count_prep(const int* __restrict__ dst, int E,
                             int* counts, int* __restrict__ rank,
                             const int* __restrict__ batch, int N, int B,
                             int* __restrict__ gstart, unsigned* __restrict__ maxPart,
                             const float* __restrict__ W1, const float* __restrict__ W2,
                             const float* __restrict__ W3,
                             const float* __restrict__ Wf1, const float* __restrict__ Wf2,
                             _Float16* __restrict__ Wt1, _Float16* __restrict__ Wt2,
                             _Float16* __restrict__ Wt3,
                             _Float16* __restrict__ Wf1t, _Float16* __restrict__ Wf2t,
                             int nbb) {
  int b = blockIdx.x;
  if (b < nbb) {
    int n = b * blockDim.x + threadIdx.x;
    if (n < 768) maxPart[n] = 0u;
    if (n >= N) return;
    int cur = batch[n];
    if (n == 0) {
      for (int g = 0; g <= cur; g++) gstart[g] = 0;
    } else {
      int prev = batch[n - 1];
      for (int g = prev + 1; g <= cur; g++) gstart[g] = n;
    }
    if (n == N - 1) {
      for (int g = cur + 1; g <= B; g++) gstart[g] = N;
    }
    return;
  }
  if (b < nbb + 19) {
    // 19 transpose tiles 128x128 f32->fp16: W1,W2,W3 (3), Wf1 (8), Wf2 (8)
    int ti = b - nbb;
    const float* src;
    _Float16* dstp_;
    int lds_, ldd_, k0, n0;
    if (ti < 3) {
      src = (ti == 0) ? W1 : (ti == 1) ? W2 : W3;
      dstp_ = (ti == 0) ? Wt1 : (ti == 1) ? Wt2 : Wt3;
      lds_ = 128; ldd_ = 128; k0 = 0; n0 = 0;
    } else if (ti < 11) {
      int j = ti - 3;
      src = Wf1; dstp_ = Wf1t; lds_ = 1024; ldd_ = 128; k0 = 0; n0 = j * 128;
    } else {
      int j = ti - 11;
      src = Wf2; dstp_ = Wf2t; lds_ = 128; ldd_ = 1024; k0 = j * 128; n0 = 0;
    }
    for (int i = threadIdx.x; i < 2048; i += 256) {
      int k = i >> 4, n8 = (i & 15) << 3;
      const float* s = &src[(size_t)(k0 + k) * lds_ + n0 + n8];
      float4 v0 = *(const float4*)&s[0];
      float4 v1 = *(const float4*)&s[4];
      dstp_[(size_t)(n0 + n8 + 0) * ldd_ + k0 + k] = (_Float16)v0.x;
      dstp_[(size_t)(n0 + n8 + 1) * ldd_ + k0 + k] = (_Float16)v0.y;
      dstp_[(size_t)(n0 + n8 + 2) * ldd_ + k0 + k] = (_Float16)v0.z;
      dstp_[(size_t)(n0 + n8 + 3) * ldd_ + k0 + k] = (_Float16)v0.w;
      dstp_[(size_t)(n0 + n8 + 4) * ldd_ + k0 + k] = (_Float16)v1.x;
      dstp_[(size_t)(n0 + n8 + 5) * ldd_ + k0 + k] = (_Float16)v1.y;
      dstp_[(size_t)(n0 + n8 + 6) * ldd_ + k0 + k] = (_Float16)v1.z;
      dstp_[(size_t)(n0 + n8 + 7) * ldd_ + k0 + k] = (_Float16)v1.w;
    }
    return;
  }
  int e = (b - nbb - 19) * 256 + threadIdx.x;
  if (e < E) rank[e] = atomicAdd(&counts[dst[e]], 1);
}

// per-node total (1 self loop + count) -> inclusive block scan
__global__ __launch_bounds__(1024) void k_scan1(const int* __restrict__ counts, int N,
                                                int* __restrict__ row_ptr, int* __restrict__ part) {
  __shared__ int tmp[1024];
  int t = threadIdx.x;
  int i = blockIdx.x * 1024 + t;
  int v = (i < N) ? 1 + counts[i] : 0;
  tmp[t] = v;
  __syncthreads();
  for (int off = 1; off < 1024; off <<= 1) {
    int u = (t >= off) ? tmp[t - off] : 0;
    __syncthreads();
    tmp[t] += u;
    __syncthreads();
  }
  if (i < N) row_ptr[i + 1] = tmp[t];
  if (t == 1023) part[blockIdx.x] = tmp[t];
}

// add prefix of block totals
__global__ __launch_bounds__(1024) void k_scan3(int* __restrict__ row_ptr,
                                                const int* __restrict__ part, int N) {
  __shared__ int s_off;
  int bi = blockIdx.x;
  if (threadIdx.x == 0) {
    int run = 0;
    for (int b = 0; b < bi; b++) run += part[b];
    s_off = run;
    if (bi == 0) row_ptr[0] = 0;
  }
  __syncthreads();
  int i = bi * 1024 + threadIdx.x;
  if (i < N) row_ptr[i + 1] += s_off;
}

// ---------------- low-LDS fp16-MFMA GEMM body (64-row tile) -------------------------------------
__device__ __forceinline__ void gemm_body(char* smem, int bx,
                                          const float* __restrict__ A32,
                                          const unsigned short* __restrict__ A16,
                                          const _Float16* __restrict__ WtG,
                                          unsigned short* __restrict__ hb,
                                          const float* __restrict__ asrc,
                                          const float* __restrict__ adst,
                                          float* __restrict__ sv, float* __restrict__ dv,
                                          unsigned* __restrict__ maxSlot, int M) {
  _Float16* Ah = (_Float16*)smem;                              // [64][AST]
  float (*sred)[64][2] = (float (*)[64][2])(smem + ABYTES);    // [4][64][2]
  int t = threadIdx.x;
  int rowbase = bx * 64;

  if (A16) {
    for (int i = t; i < 64 * 16; i += 256) {
      int r = i >> 4, c8 = (i & 15) << 3;
      int gr = rowbase + r;
      uint4 v = make_uint4(0u, 0u, 0u, 0u);
      if (gr < M) v = *(const uint4*)&A16[(size_t)gr * 128 + c8];
      *(uint4*)&Ah[r * AST + c8] = v;
    }
  } else {
    for (int i = t; i < 64 * 32; i += 256) {
      int r = i >> 5, c4 = (i & 31) << 2;
      int gr = rowbase + r;
      float4 v = make_float4(0.f, 0.f, 0.f, 0.f);
      if (gr < M) v = *(const float4*)&A32[(size_t)gr * 128 + c4];
      _Float16 tmp[4] = {(_Float16)v.x, (_Float16)v.y, (_Float16)v.z, (_Float16)v.w};
      *(short4*)&Ah[r * AST + c4] = *(short4*)tmp;
    }
  }
  __syncthreads();

  int wave = t >> 6, lane = t & 63, quad = lane >> 4, l15 = lane & 15;
  f32x4v acc[4][2];
#pragma unroll
  for (int mt = 0; mt < 4; mt++)
#pragma unroll
    for (int nt = 0; nt < 2; nt++) {
      acc[mt][nt][0] = 0.f; acc[mt][nt][1] = 0.f; acc[mt][nt][2] = 0.f; acc[mt][nt][3] = 0.f;
    }

#pragma unroll
  for (int s = 0; s < 4; s++) {
    int k0 = (s << 5) + (quad << 3);
    f16x8 af[4], bf[2];
#pragma unroll
    for (int mt = 0; mt < 4; mt++)
      af[mt] = *(f16x8*)&Ah[(mt * 16 + l15) * AST + k0];
#pragma unroll
    for (int nt = 0; nt < 2; nt++)
      bf[nt] = *(const f16x8*)&WtG[(size_t)(wave * 32 + nt * 16 + l15) * 128 + k0];
#pragma unroll
    for (int mt = 0; mt < 4; mt++)
#pragma unroll
      for (int nt = 0; nt < 2; nt++)
        acc[mt][nt] = __builtin_amdgcn_mfma_f32_16x16x32_f16(af[mt], bf[nt], acc[mt][nt], 0, 0, 0);
  }
  __syncthreads();  // all waves done reading Ah

  float avv0 = asrc[wave * 32 + l15],      avv1 = asrc[wave * 32 + 16 + l15];
  float adv0 = adst[wave * 32 + l15],      adv1 = adst[wave * 32 + 16 + l15];
  _Float16* hS16 = (_Float16*)smem;  // [64][AST]
#pragma unroll
  for (int mt = 0; mt < 4; mt++) {
#pragma unroll
    for (int rr = 0; rr < 4; rr++) {
      int row = mt * 16 + quad * 4 + rr;
      hS16[row * AST + wave * 32 + l15]      = (_Float16)acc[mt][0][rr];
      hS16[row * AST + wave * 32 + 16 + l15] = (_Float16)acc[mt][1][rr];
      float ps = acc[mt][0][rr] * avv0 + acc[mt][1][rr] * avv1;
      float pd = acc[mt][0][rr] * adv0 + acc[mt][1][rr] * adv1;
#pragma unroll
      for (int mask = 8; mask; mask >>= 1) {
        ps += __shfl_xor(ps, mask);
        pd += __shfl_xor(pd, mask);
      }
      if (l15 == 0) { sred[wave][row][0] = ps; sred[wave][row][1] = pd; }
    }
  }
  __syncthreads();

  int tx = t & 31, ty = t >> 5;
#pragma unroll
  for (int r8 = 0; r8 < 8; r8++) {
    int row = r8 * 8 + ty;
    int gr = rowbase + row;
    if (gr < M)
      *(uint2*)&hb[(size_t)gr * 128 + tx * 4] = *(const uint2*)&hS16[row * AST + tx * 4];
  }

  if (t < 64) {
    int gr = rowbase + t;
    float ps = sred[0][t][0] + sred[1][t][0] + sred[2][t][0] + sred[3][t][0];
    float pd = sred[0][t][1] + sred[1][t][1] + sred[2][t][1] + sred[3][t][1];
    float wmax = -1e30f;
    if (gr < M) { sv[gr] = ps; dv[gr] = pd; wmax = ps; }
#pragma unroll
    for (int mask = 32; mask; mask >>= 1) wmax = fmaxf(wmax, __shfl_xor(wmax, mask));
    if (t == 0) atomicMax(&maxSlot[bx & 255], enc_f(wmax));
  }
}

// ---------------- segment-softmax aggregation body (node range [n0,n1), 1 wave/node) ------------
// r8 body: 48 VGPR, ~66us/layer. At the gather/cache-BW equilibrium (~6.4 TB/s effective);
// scheduling/VALU micro-opts exhausted (r6/r8 both neutral-or-worse).
__device__ __forceinline__ void agg_body(int aggBlk,
                                         const unsigned short* __restrict__ hb,
                                         const float* __restrict__ sv,
                                         const float* __restrict__ dv,
                                         const int* __restrict__ row_ptr,
                                         const int* __restrict__ col,
                                         const float* __restrict__ bias,
                                         const unsigned* __restrict__ maxSlot,
                                         unsigned short* __restrict__ out16,
                                         int n0, int n1, int relu) {
  int wid = n0 + aggBlk * 4 + (threadIdx.x >> 6);
  int lane = threadIdx.x & 63;
  if (wid >= n1) return;

  unsigned mp = max(max(maxSlot[lane], maxSlot[lane + 64]),
                    max(maxSlot[lane + 128], maxSlot[lane + 192]));
#pragma unroll
  for (int off = 32; off; off >>= 1) mp = max(mp, __shfl_xor(mp, off));
  float maxS = dec_f(mp);

  int beg = row_ptr[wid], end = row_ptr[wid + 1];
  float dn = dv[wid];
  float m = maxS + dn;
  m = (m > 0.f) ? m : NEG_SLOPE * m;  // upper bound on all incoming e (leaky_relu monotone)

  int g = lane >> 4, sub = lane & 15;
  const uint32_t* hbu = (const uint32_t*)hb;
  float acc[8];
#pragma unroll
  for (int k = 0; k < 8; k++) acc[k] = 0.f;
  float dsum = 0.f;

#define FETCH_SLOT(K, W, H)                                                \
  {                                                                        \
    int sl = ((K) << 2) + g;                                               \
    int sn = __shfl(sn_l, sl);                                             \
    W = __shfl(w_l, sl);                                                   \
    H = make_uint4(0u, 0u, 0u, 0u);                                        \
    if (sl < cnt) H = *(const uint4*)(hbu + (size_t)sn * 64 + sub * 4);    \
  }
#define ACC_SLOT(W, H)                                                     \
  {                                                                        \
    const _Float16* hp = (const _Float16*)&H;                              \
    _Pragma("unroll")                                                      \
    for (int q = 0; q < 8; q++) acc[q] += W * (float)hp[q];                \
  }

  for (int base = beg; base < end; base += 64) {
    int cnt = min(end - base, 64);

    // phase 1: vectorized edge prep across all 64 lanes
    int sn_l = 0;
    float w_l = 0.f;
    if (lane < cnt) {
      sn_l = col[base + lane];
      float e = sv[sn_l] + dn;
      e = (e > 0.f) ? e : NEG_SLOPE * e;
      w_l = __expf(e - m);
      dsum += w_l;
    }

    // phase 2: 4-deep rotation gather, no remainder (slots >= cnt contribute exactly 0)
    int kmaxW4 = (((cnt + 3) >> 2) + 3) & ~3;  // wave-uniform, 4..16
    float wA, wB, wC, wD;
    uint4 hA, hB, hC, hD;
    FETCH_SLOT(0, wA, hA);
    FETCH_SLOT(1, wB, hB);
    FETCH_SLOT(2, wC, hC);
    FETCH_SLOT(3, wD, hD);
    for (int k = 4; k < kmaxW4; k += 4) {
      ACC_SLOT(wA, hA); FETCH_SLOT(k + 0, wA, hA);
      ACC_SLOT(wB, hB); FETCH_SLOT(k + 1, wB, hB);
      ACC_SLOT(wC, hC); FETCH_SLOT(k + 2, wC, hC);
      ACC_SLOT(wD, hD); FETCH_SLOT(k + 3, wD, hD);
    }
    ACC_SLOT(wA, hA);
    ACC_SLOT(wB, hB);
    ACC_SLOT(wC, hC);
    ACC_SLOT(wD, hD);
  }

#pragma unroll
  for (int off = 1; off < 64; off <<= 1) dsum += __shfl_xor(dsum, off);
#pragma unroll
  for (int k = 0; k < 8; k++) {
    acc[k] += __shfl_xor(acc[k], 16);
    acc[k] += __shfl_xor(acc[k], 32);
  }
  if (lane < 16) {
    float inv = 1.f / dsum;
    float o[8];
    const float* bp = &bias[sub * 8];
#pragma unroll
    for (int k = 0; k < 8; k++) {
      o[k] = acc[k] * inv + bp[k];
      if (relu) o[k] = fmaxf(o[k], 0.f);
    }
    _Float16 q[8];
#pragma unroll
    for (int k = 0; k < 8; k++) q[k] = (_Float16)o[k];
    *(uint4*)&out16[(size_t)wid * 128 + sub * 8] = *(uint4*)q;
  }
}

__global__ __launch_bounds__(256) void k_agg(const unsigned short* __restrict__ hb,
                                             const float* __restrict__ sv,
                                             const float* __restrict__ dv,
                                             const int* __restrict__ row_ptr,
                                             const int* __restrict__ col,
                                             const float* __restrict__ bias,
                                             const unsigned* __restrict__ maxSlot,
                                             unsigned short* __restrict__ out16,
                                             int n0, int n1, int relu) {
  agg_body((int)blockIdx.x, hb, sv, dv, row_ptr, col, bias, maxSlot, out16, n0, n1, relu);
}

// ---------------- FUSED: agg (layer i, rows [n0,n1)) || gemm (layer i+1, tiles [0,Gh1)) ---------
// Race-free by ping-pong: agg reads hb_r/sv_r/dv_r (layer i), gemm writes hb_w/... (layer i+1,
// DIFFERENT buffers). a16 shared: gemm reads rows < Gh1*64 <= n0 (done last launch), agg writes
// rows >= n0 — disjoint 256B-aligned rows. gemm LDS 19.5KB -> 8 blk/CU = the 32-wave cap, so agg
// co-residency is not LDS-capped (unlike the r1/r3 atomic-kernel failures).
__global__ __launch_bounds__(256) void k_agg_gemm(const unsigned short* __restrict__ hb_r,
                                                  const float* __restrict__ sv_r,
                                                  const float* __restrict__ dv_r,
                                                  const int* __restrict__ row_ptr,
                                                  const int* __restrict__ col,
                                                  const float* __restrict__ bias,
                                                  const unsigned* __restrict__ maxSlot_r,
                                                  unsigned short* __restrict__ a16,
                                                  int n0, int n1, int relu,
                                                  const _Float16* __restrict__ WtG,
                                                  unsigned short* __restrict__ hb_w,
                                                  const float* __restrict__ asrc,
                                                  const float* __restrict__ adst,
                                                  float* __restrict__ sv_w,
                                                  float* __restrict__ dv_w,
                                                  unsigned* __restrict__ maxSlot_w,
                                                  int Gh1, int R, int N) {
  __shared__ __align__(16) char smem[SMEM_BYTES];
  int b = (int)blockIdx.x;
  int half = R >> 1;
  bool isGemm = ((b % R) == half) && ((b / R) < Gh1);
  if (isGemm) {
    gemm_body(smem, b / R, (const float*)nullptr, a16, WtG,
              hb_w, asrc, adst, sv_w, dv_w, maxSlot_w, N);
  } else {
    int nGB = (b >= half) ? min((b - half) / R + 1, Gh1) : 0;
    agg_body(b - nGB, hb_r, sv_r, dv_r, row_ptr, col, bias, maxSlot_r, a16, n0, n1, relu);
  }
}

// ---------------- FUSED: CSR fill (scatter) || layer-0 GEMM, interleaved 9:1 --------------------
__global__ __launch_bounds__(256) void k_fill_gemm(const int* __restrict__ src,
                                                   const int* __restrict__ dst,
                                                   const int* __restrict__ rank, int E, int N,
                                                   const int* __restrict__ row_ptr,
                                                   int* __restrict__ col,
                                                   const float* __restrict__ A32,
                                                   const _Float16* __restrict__ WtG,
                                                   unsigned short* __restrict__ hb,
                                                   const float* __restrict__ asrc,
                                                   const float* __restrict__ adst,
                                                   float* __restrict__ sv, float* __restrict__ dv,
                                                   unsigned* __restrict__ maxSlot, int Gg) {
  __shared__ __align__(16) char smem[SMEM_BYTES];
  int b = (int)blockIdx.x;
  bool isGemm = ((b % 9) == 4) && ((b / 9) < Gg);
  if (isGemm) {
    gemm_body(smem, b / 9, A32, (const unsigned short*)nullptr, WtG,
              hb, asrc, adst, sv, dv, maxSlot, N);
  } else {
    int nGemmBefore = (b >= 4) ? min((b - 4) / 9 + 1, Gg) : 0;
    int i = (b - nGemmBefore) * 256 + threadIdx.x;
    if (i < N) col[row_ptr[i]] = i;  // self loop first in each row
    int e = i - N;
    if (e >= 0 && e < E) col[row_ptr[dst[e]] + 1 + rank[e]] = src[e];
  }
}

// ---------------- GEMM over tile range [bxOff, bxOff + gridDim) ----------------
__global__ __launch_bounds__(256) void k_gemm_range(const unsigned short* __restrict__ A16,
                                                    const _Float16* __restrict__ WtG,
                                                    unsigned short* __restrict__ hb,
                                                    const float* __restrict__ asrc,
                                                    const float* __restrict__ adst,
                                                    float* __restrict__ sv, float* __restrict__ dv,
                                                    unsigned* __restrict__ maxSlot, int M, int bxOff) {
  __shared__ __align__(16) char smem[SMEM_BYTES];
  gemm_body(smem, bxOff + (int)blockIdx.x, (const float*)nullptr, A16, WtG,
            hb, asrc, adst, sv, dv, maxSlot, M);
}

// ---------------- mean pool + relu -> fp16, one block per graph ----------------
__global__ __launch_bounds__(256) void k_pool(const unsigned short* __restrict__ h16,
                                              const int* __restrict__ gstart,
                                              unsigned short* __restrict__ pooled16, int B) {
  __shared__ float red[4][128];
  int b = blockIdx.x, t = threadIdx.x;
  int c = t & 63, seg = t >> 6;
  int s0 = gstart[b], s1 = gstart[b + 1];
  int cnt = s1 - s0;
  int per = (cnt + 3) >> 2;
  int n0 = s0 + seg * per;
  int n1 = min(n0 + per, s1);
  const uint32_t* hu = (const uint32_t*)h16;
  float a0 = 0.f, a1 = 0.f;
  for (int n = n0; n < n1; n++) {
    union { uint32_t u; _Float16 h[2]; } cv;
    cv.u = hu[(size_t)n * 64 + c];
    a0 += (float)cv.h[0];
    a1 += (float)cv.h[1];
  }
  if (seg) { red[seg][2 * c] = a0; red[seg][2 * c + 1] = a1; }
  __syncthreads();
  if (seg == 0) {
    a0 += red[1][2 * c] + red[2][2 * c] + red[3][2 * c];
    a1 += red[1][2 * c + 1] + red[2][2 * c + 1] + red[3][2 * c + 1];
    float inv = 1.f / (float)(cnt > 0 ? cnt : 1);
    union { uint32_t u; _Float16 h[2]; } ov;
    ov.h[0] = (_Float16)fmaxf(a0 * inv, 0.f);
    ov.h[1] = (_Float16)fmaxf(a1 * inv, 0.f);
    *(uint32_t*)&pooled16[(size_t)b * 128 + 2 * c] = ov.u;
  }
}

// ---------------- MFMA MLP layer 1: H1 = relu(P @ Wf1 + bf1), fp16 out ----------------
__global__ __launch_bounds__(256) void k_mlp1(const unsigned short* __restrict__ P16,
                                              const _Float16* __restrict__ Wf1t,
                                              const float* __restrict__ bf1,
                                              unsigned short* __restrict__ H1g, int B, int nRow) {
  __shared__ __align__(16) _Float16 Ah[64 * AST];
  int bx = (int)blockIdx.x;
  int rowt = bx % nRow, colt = bx / nRow;
  int rowbase = rowt * 64;
  int t = threadIdx.x;

  for (int i = t; i < 64 * 16; i += 256) {
    int r = i >> 4, c8 = (i & 15) << 3;
    int gr = rowbase + r;
    uint4 v = make_uint4(0u, 0u, 0u, 0u);
    if (gr < B) v = *(const uint4*)&P16[(size_t)gr * 128 + c8];
    *(uint4*)&Ah[r * AST + c8] = v;
  }
  __syncthreads();

  int wave = t >> 6, lane = t & 63, quad = lane >> 4, l15 = lane & 15;
  int colbase = colt * 128 + wave * 32;
  f32x4v acc[4][2];
#pragma unroll
  for (int mt = 0; mt < 4; mt++)
#pragma unroll
    for (int nt = 0; nt < 2; nt++) {
      acc[mt][nt][0] = 0.f; acc[mt][nt][1] = 0.f; acc[mt][nt][2] = 0.f; acc[mt][nt][3] = 0.f;
    }
#pragma unroll
  for (int s = 0; s < 4; s++) {
    int k0 = (s << 5) + (quad << 3);
    f16x8 af[4], bf[2];
#pragma unroll
    for (int mt = 0; mt < 4; mt++)
      af[mt] = *(f16x8*)&Ah[(mt * 16 + l15) * AST + k0];
#pragma unroll
    for (int nt = 0; nt < 2; nt++)
      bf[nt] = *(const f16x8*)&Wf1t[(size_t)(colbase + nt * 16 + l15) * 128 + k0];
#pragma unroll
    for (int mt = 0; mt < 4; mt++)
#pragma unroll
      for (int nt = 0; nt < 2; nt++)
        acc[mt][nt] = __builtin_amdgcn_mfma_f32_16x16x32_f16(af[mt], bf[nt], acc[mt][nt], 0, 0, 0);
  }

  float b0 = bf1[colbase + l15], b1 = bf1[colbase + 16 + l15];
#pragma unroll
  for (int mt = 0; mt < 4; mt++)
#pragma unroll
    for (int rr = 0; rr < 4; rr++) {
      int gr = rowbase + mt * 16 + quad * 4 + rr;
      if (gr < B) {
        H1g[(size_t)gr * 1024 + colbase + l15] =
            (unsigned short)__builtin_bit_cast(unsigned short, (_Float16)fmaxf(acc[mt][0][rr] + b0, 0.f));
        H1g[(size_t)gr * 1024 + colbase + 16 + l15] =
            (unsigned short)__builtin_bit_cast(unsigned short, (_Float16)fmaxf(acc[mt][1][rr] + b1, 0.f));
      }
    }
}

// ---------------- MFMA MLP layer 2: out = H1 @ Wf2 + bf2 (f32) ----------------
__global__ __launch_bounds__(256) void k_mlp2(const unsigned short* __restrict__ H1g,
                                              const _Float16* __restrict__ Wf2t,
                                              const float* __restrict__ bf2,
                                              float* __restrict__ out, int B) {
  __shared__ __align__(16) _Float16 Ah[64 * AST];
  int rowbase = (int)blockIdx.x * 64;
  int t = threadIdx.x;
  int wave = t >> 6, lane = t & 63, quad = lane >> 4, l15 = lane & 15;

  f32x4v acc[4][2];
#pragma unroll
  for (int mt = 0; mt < 4; mt++)
#pragma unroll
    for (int nt = 0; nt < 2; nt++) {
      acc[mt][nt][0] = 0.f; acc[mt][nt][1] = 0.f; acc[mt][nt][2] = 0.f; acc[mt][nt][3] = 0.f;
    }

  for (int kc = 0; kc < 8; kc++) {
    for (int i = t; i < 64 * 16; i += 256) {
      int r = i >> 4, c8 = (i & 15) << 3;
      int gr = rowbase + r;
      uint4 v = make_uint4(0u, 0u, 0u, 0u);
      if (gr < B) v = *(const uint4*)&H1g[(size_t)gr * 1024 + kc * 128 + c8];
      *(uint4*)&Ah[r * AST + c8] = v;
    }
    __syncthreads();
#pragma unroll
    for (int s = 0; s < 4; s++) {
      int k0 = (s << 5) + (quad << 3);
      f16x8 af[4], bf[2];
#pragma unroll
      for (int mt = 0; mt < 4; mt++)
        af[mt] = *(f16x8*)&Ah[(mt * 16 + l15) * AST + k0];
#pragma unroll
      for (int nt = 0; nt < 2; nt++)
        bf[nt] = *(const f16x8*)&Wf2t[(size_t)(wave * 32 + nt * 16 + l15) * 1024 + kc * 128 + k0];
#pragma unroll
      for (int mt = 0; mt < 4; mt++)
#pragma unroll
        for (int nt = 0; nt < 2; nt++)
          acc[mt][nt] = __builtin_amdgcn_mfma_f32_16x16x32_f16(af[mt], bf[nt], acc[mt][nt], 0, 0, 0);
    }
    __syncthreads();
  }

  int col0 = wave * 32 + l15, col1 = col0 + 16;
  float b0 = bf2[col0], b1 = bf2[col1];
#pragma unroll
  for (int mt = 0; mt < 4; mt++)
#pragma unroll
    for (int rr = 0; rr < 4; rr++) {
      int gr = rowbase + mt * 16 + quad * 4 + rr;
      if (gr < B) {
        out[(size_t)gr * 128 + col0] = acc[mt][0][rr] + b0;
        out[(size_t)gr * 128 + col1] = acc[mt][1][rr] + b1;
      }
    }
}

extern "C" void kernel_launch(void* const* d_in, const int* in_sizes, int n_in,
                              void* d_out, int out_size, void* d_ws, size_t ws_size,
                              hipStream_t stream) {
  const float* x     = (const float*)d_in[0];
  const int*   ei    = (const int*)d_in[1];
  const int*   batch = (const int*)d_in[3];
  const float* W1 = (const float*)d_in[4];
  const float* as1 = (const float*)d_in[5];
  const float* ad1 = (const float*)d_in[6];
  const float* b1 = (const float*)d_in[7];
  const float* W2 = (const float*)d_in[8];
  const float* as2 = (const float*)d_in[9];
  const float* ad2 = (const float*)d_in[10];
  const float* b2 = (const float*)d_in[11];
  const float* W3 = (const float*)d_in[12];
  const float* as3 = (const float*)d_in[13];
  const float* ad3 = (const float*)d_in[14];
  const float* b3 = (const float*)d_in[15];
  const float* Wf1 = (const float*)d_in[16];
  const float* bf1 = (const float*)d_in[17];
  const float* Wf2 = (const float*)d_in[18];
  const float* bf2 = (const float*)d_in[19];

  const int N = in_sizes[0] / 128;
  const int E = in_sizes[1] / 2;
  const int B = out_size / 128;

  char* base_ws = (char*)d_ws;
  size_t off = 0;
  auto carve = [&](size_t bytes) -> void* {
    off = (off + 255) & ~(size_t)255;
    void* p = base_ws + off;
    off += bytes;
    return p;
  };
  int* counts   = (int*)carve((size_t)N * 4);
  int* row_ptr  = (int*)carve((size_t)(N + 1) * 4);
  int* rank     = (int*)carve((size_t)E * 4);
  int* col      = (int*)carve((size_t)(E + N) * 4);
  int* part     = (int*)carve(1024 * 4);
  int* gstart   = (int*)carve((size_t)(B + 1) * 4);
  unsigned* maxPart = (unsigned*)carve(768 * 4);
  float* svA    = (float*)carve((size_t)N * 4);
  float* dvA    = (float*)carve((size_t)N * 4);
  float* svB    = (float*)carve((size_t)N * 4);
  float* dvB    = (float*)carve((size_t)N * 4);
  unsigned short* hbA = (unsigned short*)carve((size_t)N * 128 * 2);
  unsigned short* hbB = (unsigned short*)carve((size_t)N * 128 * 2);
  unsigned short* a16 = (unsigned short*)carve((size_t)N * 128 * 2);
  unsigned short* pooled16 = (unsigned short*)carve((size_t)B * 128 * 2);
  unsigned short* H1g = (unsigned short*)carve((size_t)B * 1024 * 2);
  _Float16* Wt1 = (_Float16*)carve(128 * 128 * 2);
  _Float16* Wt2 = (_Float16*)carve(128 * 128 * 2);
  _Float16* Wt3 = (_Float16*)carve(128 * 128 * 2);
  _Float16* Wf1t = (_Float16*)carve((size_t)1024 * 128 * 2);
  _Float16* Wf2t = (_Float16*)carve((size_t)128 * 1024 * 2);

  const int* srcp = ei;
  const int* dstp = ei + E;
  const int nb = (N + 1023) / 1024;
  const int Gg = (N + 63) / 64;                 // 64-row gemm tiles (full)
  const int Gf = (E + N + 255) / 256;           // fill blocks
  const int nbb = (N + 255) / 256;              // bounds blocks
  const int Cb = (E + 255) / 256;               // count blocks
  const int nRow = (B + 63) / 64;               // mlp row tiles

  // half split for agg||gemm pipeline (h1 boundary at a 64-row tile edge)
  int Nh = ((N / 2 + 63) / 64) * 64;
  if (Nh >= N) Nh = (N > 64) ? ((N - 64) / 64) * 64 : 0;
  const int Gh1 = Nh / 64;                      // gemm tiles fully inside h1
  const int Ah1 = (Nh + 3) / 4;                 // agg blocks for h1
  const int Ah2 = (N - Nh + 3) / 4;             // agg blocks for h2
  int R = (Gh1 > 0) ? (Ah2 + Gh1) / Gh1 : 2;    // interleave period
  if (R < 2) R = 2;

  hipMemsetAsync(counts, 0, (size_t)N * 4, stream);
  hipLaunchKernelGGL(k_count_prep, dim3(nbb + 19 + Cb), dim3(256), 0, stream,
                     dstp, E, counts, rank,
                     batch, N, B, gstart, maxPart,
                     W1, W2, W3, Wf1, Wf2, Wt1, Wt2, Wt3, Wf1t, Wf2t, nbb);
  hipLaunchKernelGGL(k_scan1, dim3(nb), dim3(1024), 0, stream, counts, N, row_ptr, part);
  hipLaunchKernelGGL(k_scan3, dim3(nb), dim3(1024), 0, stream, row_ptr, part, N);

  // fill (CSR scatter) || gemm layer 0 -> hbA/svA/dvA/slot0
  hipLaunchKernelGGL(k_fill_gemm, dim3(Gf + Gg), dim3(256), 0, stream,
                     srcp, dstp, rank, E, N, row_ptr, col,
                     x, Wt1, hbA, as1, ad1, svA, dvA, maxPart + 0 * 256, Gg);

  // ---- layer 0 agg + layer 1 gemm pipeline (ping-pong A->B) ----
  hipLaunchKernelGGL(k_agg, dim3(Ah1), dim3(256), 0, stream,
                     hbA, svA, dvA, row_ptr, col, b1, maxPart + 0 * 256, a16, 0, Nh, 0);
  hipLaunchKernelGGL(k_agg_gemm, dim3(Ah2 + Gh1), dim3(256), 0, stream,
                     hbA, svA, dvA, row_ptr, col, b1, maxPart + 0 * 256, a16, Nh, N, 0,
                     Wt2, hbB, as2, ad2, svB, dvB, maxPart + 1 * 256, Gh1, R, N);
  hipLaunchKernelGGL(k_gemm_range, dim3(Gg - Gh1), dim3(256), 0, stream,
                     a16, Wt2, hbB, as2, ad2, svB, dvB, maxPart + 1 * 256, N, Gh1);

  // ---- layer 1 agg + layer 2 gemm pipeline (ping-pong B->A) ----
  hipLaunchKernelGGL(k_agg, dim3(Ah1), dim3(256), 0, stream,
                     hbB, svB, dvB, row_ptr, col, b2, maxPart + 1 * 256, a16, 0, Nh, 1);
  hipLaunchKernelGGL(k_agg_gemm, dim3(Ah2 + Gh1), dim3(256), 0, stream,
                     hbB, svB, dvB, row_ptr, col, b2, maxPart + 1 * 256, a16, Nh, N, 1,
                     Wt3, hbA, as3, ad3, svA, dvA, maxPart + 2 * 256, Gh1, R, N);
  hipLaunchKernelGGL(k_gemm_range, dim3(Gg - Gh1), dim3(256), 0, stream,
                     a16, Wt3, hbA, as3, ad3, svA, dvA, maxPart + 2 * 256, N, Gh1);

  // ---- layer 2 agg (full) ----
  hipLaunchKernelGGL(k_agg, dim3((N + 3) / 4), dim3(256), 0, stream,
                     hbA, svA, dvA, row_ptr, col, b3, maxPart + 2 * 256, a16, 0, N, 1);

  hipLaunchKernelGGL(k_pool, dim3(B), dim3(256), 0, stream, a16, gstart, pooled16, B);
  hipLaunchKernelGGL(k_mlp1, dim3(nRow * 8), dim3(256), 0, stream,
                     pooled16, Wf1t, bf1, H1g, B, nRow);
  hipLaunchKernelGGL(k_mlp2, dim3(nRow), dim3(256), 0, stream,
                     H1g, Wf2t, bf2, (float*)d_out, B);
}

// Round 11
// 499.577 us; speedup vs baseline: 1.1292x; 1.1292x over previous
//
#include <hip/hip_runtime.h>
#include <cstdint>
#include <cstddef>

#define NEG_SLOPE 0.2f

typedef _Float16 f16x8 __attribute__((ext_vector_type(8)));
typedef float f32x4v __attribute__((ext_vector_type(4)));

__device__ __forceinline__ unsigned enc_f(float f) {
  unsigned u = __float_as_uint(f);
  return (u & 0x80000000u) ? ~u : (u | 0x80000000u);
}
__device__ __forceinline__ float dec_f(unsigned u) {
  return (u & 0x80000000u) ? __uint_as_float(u ^ 0x80000000u) : __uint_as_float(~u);
}

#define AST 136
#define ABYTES (64 * AST * 2)                 // 17408: A tile (fp16), aliased by fp16 h stage
#define SMEM_BYTES (ABYTES + 4 * 64 * 2 * 4)  // + 2KB cross-wave s/d partials = 19456

// -------- FUSED: count_rank (atomic floor) || prep (bounds + W->fp16 transposes) ----------------
// Both parts LDS-free -> no occupancy interference with the returning-atomic pipeline.
// LESSON (r1/r3/r10): heterogeneous block fusion only pays when the co-resident path is
// resource-light; any VGPR/LDS inflation on the latency-bound path loses more to occupancy
// than the overlap gains. counts[] zeroed by hipMemsetAsync beforehand.
__global__ void k_count_prep(const int* __restrict__ dst, int E,
                             int* counts, int* __restrict__ rank,
                             const int* __restrict__ batch, int N, int B,
                             int* __restrict__ gstart, unsigned* __restrict__ maxPart,
                             const float* __restrict__ W1, const float* __restrict__ W2,
                             const float* __restrict__ W3,
                             const float* __restrict__ Wf1, const float* __restrict__ Wf2,
                             _Float16* __restrict__ Wt1, _Float16* __restrict__ Wt2,
                             _Float16* __restrict__ Wt3,
                             _Float16* __restrict__ Wf1t, _Float16* __restrict__ Wf2t,
                             int nbb) {
  int b = blockIdx.x;
  if (b < nbb) {
    int n = b * blockDim.x + threadIdx.x;
    if (n < 768) maxPart[n] = 0u;
    if (n >= N) return;
    int cur = batch[n];
    if (n == 0) {
      for (int g = 0; g <= cur; g++) gstart[g] = 0;
    } else {
      int prev = batch[n - 1];
      for (int g = prev + 1; g <= cur; g++) gstart[g] = n;
    }
    if (n == N - 1) {
      for (int g = cur + 1; g <= B; g++) gstart[g] = N;
    }
    return;
  }
  if (b < nbb + 19) {
    // 19 transpose tiles 128x128 f32->fp16: W1,W2,W3 (3), Wf1 (8), Wf2 (8)
    int ti = b - nbb;
    const float* src;
    _Float16* dstp_;
    int lds_, ldd_, k0, n0;
    if (ti < 3) {
      src = (ti == 0) ? W1 : (ti == 1) ? W2 : W3;
      dstp_ = (ti == 0) ? Wt1 : (ti == 1) ? Wt2 : Wt3;
      lds_ = 128; ldd_ = 128; k0 = 0; n0 = 0;
    } else if (ti < 11) {
      int j = ti - 3;
      src = Wf1; dstp_ = Wf1t; lds_ = 1024; ldd_ = 128; k0 = 0; n0 = j * 128;
    } else {
      int j = ti - 11;
      src = Wf2; dstp_ = Wf2t; lds_ = 128; ldd_ = 1024; k0 = j * 128; n0 = 0;
    }
    for (int i = threadIdx.x; i < 2048; i += 256) {
      int k = i >> 4, n8 = (i & 15) << 3;
      const float* s = &src[(size_t)(k0 + k) * lds_ + n0 + n8];
      float4 v0 = *(const float4*)&s[0];
      float4 v1 = *(const float4*)&s[4];
      dstp_[(size_t)(n0 + n8 + 0) * ldd_ + k0 + k] = (_Float16)v0.x;
      dstp_[(size_t)(n0 + n8 + 1) * ldd_ + k0 + k] = (_Float16)v0.y;
      dstp_[(size_t)(n0 + n8 + 2) * ldd_ + k0 + k] = (_Float16)v0.z;
      dstp_[(size_t)(n0 + n8 + 3) * ldd_ + k0 + k] = (_Float16)v0.w;
      dstp_[(size_t)(n0 + n8 + 4) * ldd_ + k0 + k] = (_Float16)v1.x;
      dstp_[(size_t)(n0 + n8 + 5) * ldd_ + k0 + k] = (_Float16)v1.y;
      dstp_[(size_t)(n0 + n8 + 6) * ldd_ + k0 + k] = (_Float16)v1.z;
      dstp_[(size_t)(n0 + n8 + 7) * ldd_ + k0 + k] = (_Float16)v1.w;
    }
    return;
  }
  int e = (b - nbb - 19) * 256 + threadIdx.x;
  if (e < E) rank[e] = atomicAdd(&counts[dst[e]], 1);
}

// per-node total (1 self loop + count) -> inclusive block scan
__global__ __launch_bounds__(1024) void k_scan1(const int* __restrict__ counts, int N,
                                                int* __restrict__ row_ptr, int* __restrict__ part) {
  __shared__ int tmp[1024];
  int t = threadIdx.x;
  int i = blockIdx.x * 1024 + t;
  int v = (i < N) ? 1 + counts[i] : 0;
  tmp[t] = v;
  __syncthreads();
  for (int off = 1; off < 1024; off <<= 1) {
    int u = (t >= off) ? tmp[t - off] : 0;
    __syncthreads();
    tmp[t] += u;
    __syncthreads();
  }
  if (i < N) row_ptr[i + 1] = tmp[t];
  if (t == 1023) part[blockIdx.x] = tmp[t];
}

// add prefix of block totals
__global__ __launch_bounds__(1024) void k_scan3(int* __restrict__ row_ptr,
                                                const int* __restrict__ part, int N) {
  __shared__ int s_off;
  int bi = blockIdx.x;
  if (threadIdx.x == 0) {
    int run = 0;
    for (int b = 0; b < bi; b++) run += part[b];
    s_off = run;
    if (bi == 0) row_ptr[0] = 0;
  }
  __syncthreads();
  int i = bi * 1024 + threadIdx.x;
  if (i < N) row_ptr[i + 1] += s_off;
}

// ---------------- low-LDS fp16-MFMA GEMM body (64-row tile) -------------------------------------
// B-fragments read directly from precomputed global Wt (fp16, transposed; L1/L2-resident).
// sv/dv computed in-register from f32 accumulators (exact); only fp16 h staged in LDS.
__device__ __forceinline__ void gemm_body(char* smem, int bx,
                                          const float* __restrict__ A32,
                                          const unsigned short* __restrict__ A16,
                                          const _Float16* __restrict__ WtG,
                                          unsigned short* __restrict__ hb,
                                          const float* __restrict__ asrc,
                                          const float* __restrict__ adst,
                                          float* __restrict__ sv, float* __restrict__ dv,
                                          unsigned* __restrict__ maxSlot, int M) {
  _Float16* Ah = (_Float16*)smem;                              // [64][AST]
  float (*sred)[64][2] = (float (*)[64][2])(smem + ABYTES);    // [4][64][2]
  int t = threadIdx.x;
  int rowbase = bx * 64;

  if (A16) {
    for (int i = t; i < 64 * 16; i += 256) {
      int r = i >> 4, c8 = (i & 15) << 3;
      int gr = rowbase + r;
      uint4 v = make_uint4(0u, 0u, 0u, 0u);
      if (gr < M) v = *(const uint4*)&A16[(size_t)gr * 128 + c8];
      *(uint4*)&Ah[r * AST + c8] = v;
    }
  } else {
    for (int i = t; i < 64 * 32; i += 256) {
      int r = i >> 5, c4 = (i & 31) << 2;
      int gr = rowbase + r;
      float4 v = make_float4(0.f, 0.f, 0.f, 0.f);
      if (gr < M) v = *(const float4*)&A32[(size_t)gr * 128 + c4];
      _Float16 tmp[4] = {(_Float16)v.x, (_Float16)v.y, (_Float16)v.z, (_Float16)v.w};
      *(short4*)&Ah[r * AST + c4] = *(short4*)tmp;
    }
  }
  __syncthreads();

  int wave = t >> 6, lane = t & 63, quad = lane >> 4, l15 = lane & 15;
  f32x4v acc[4][2];
#pragma unroll
  for (int mt = 0; mt < 4; mt++)
#pragma unroll
    for (int nt = 0; nt < 2; nt++) {
      acc[mt][nt][0] = 0.f; acc[mt][nt][1] = 0.f; acc[mt][nt][2] = 0.f; acc[mt][nt][3] = 0.f;
    }

#pragma unroll
  for (int s = 0; s < 4; s++) {
    int k0 = (s << 5) + (quad << 3);
    f16x8 af[4], bf[2];
#pragma unroll
    for (int mt = 0; mt < 4; mt++)
      af[mt] = *(f16x8*)&Ah[(mt * 16 + l15) * AST + k0];
#pragma unroll
    for (int nt = 0; nt < 2; nt++)
      bf[nt] = *(const f16x8*)&WtG[(size_t)(wave * 32 + nt * 16 + l15) * 128 + k0];
#pragma unroll
    for (int mt = 0; mt < 4; mt++)
#pragma unroll
      for (int nt = 0; nt < 2; nt++)
        acc[mt][nt] = __builtin_amdgcn_mfma_f32_16x16x32_f16(af[mt], bf[nt], acc[mt][nt], 0, 0, 0);
  }
  __syncthreads();  // all waves done reading Ah

  float avv0 = asrc[wave * 32 + l15],      avv1 = asrc[wave * 32 + 16 + l15];
  float adv0 = adst[wave * 32 + l15],      adv1 = adst[wave * 32 + 16 + l15];
  _Float16* hS16 = (_Float16*)smem;  // [64][AST]
#pragma unroll
  for (int mt = 0; mt < 4; mt++) {
#pragma unroll
    for (int rr = 0; rr < 4; rr++) {
      int row = mt * 16 + quad * 4 + rr;
      hS16[row * AST + wave * 32 + l15]      = (_Float16)acc[mt][0][rr];
      hS16[row * AST + wave * 32 + 16 + l15] = (_Float16)acc[mt][1][rr];
      float ps = acc[mt][0][rr] * avv0 + acc[mt][1][rr] * avv1;
      float pd = acc[mt][0][rr] * adv0 + acc[mt][1][rr] * adv1;
#pragma unroll
      for (int mask = 8; mask; mask >>= 1) {
        ps += __shfl_xor(ps, mask);
        pd += __shfl_xor(pd, mask);
      }
      if (l15 == 0) { sred[wave][row][0] = ps; sred[wave][row][1] = pd; }
    }
  }
  __syncthreads();

  int tx = t & 31, ty = t >> 5;
#pragma unroll
  for (int r8 = 0; r8 < 8; r8++) {
    int row = r8 * 8 + ty;
    int gr = rowbase + row;
    if (gr < M)
      *(uint2*)&hb[(size_t)gr * 128 + tx * 4] = *(const uint2*)&hS16[row * AST + tx * 4];
  }

  if (t < 64) {
    int gr = rowbase + t;
    float ps = sred[0][t][0] + sred[1][t][0] + sred[2][t][0] + sred[3][t][0];
    float pd = sred[0][t][1] + sred[1][t][1] + sred[2][t][1] + sred[3][t][1];
    float wmax = -1e30f;
    if (gr < M) { sv[gr] = ps; dv[gr] = pd; wmax = ps; }
#pragma unroll
    for (int mask = 32; mask; mask >>= 1) wmax = fmaxf(wmax, __shfl_xor(wmax, mask));
    if (t == 0) atomicMax(&maxSlot[bx & 255], enc_f(wmax));
  }
}

// ---------------- FUSED: CSR fill (scatter) || layer-0 GEMM, interleaved 9:1 --------------------
// fill's scatter path is 4-VGPR/0-extra-LDS -> tolerates the gemm LDS cap (r2-proven).
__global__ __launch_bounds__(256) void k_fill_gemm(const int* __restrict__ src,
                                                   const int* __restrict__ dst,
                                                   const int* __restrict__ rank, int E, int N,
                                                   const int* __restrict__ row_ptr,
                                                   int* __restrict__ col,
                                                   const float* __restrict__ A32,
                                                   const _Float16* __restrict__ WtG,
                                                   unsigned short* __restrict__ hb,
                                                   const float* __restrict__ asrc,
                                                   const float* __restrict__ adst,
                                                   float* __restrict__ sv, float* __restrict__ dv,
                                                   unsigned* __restrict__ maxSlot, int Gg) {
  __shared__ __align__(16) char smem[SMEM_BYTES];
  int b = (int)blockIdx.x;
  bool isGemm = ((b % 9) == 4) && ((b / 9) < Gg);
  if (isGemm) {
    gemm_body(smem, b / 9, A32, (const unsigned short*)nullptr, WtG,
              hb, asrc, adst, sv, dv, maxSlot, N);
  } else {
    int nGemmBefore = (b >= 4) ? min((b - 4) / 9 + 1, Gg) : 0;
    int i = (b - nGemmBefore) * 256 + threadIdx.x;
    if (i < N) col[row_ptr[i]] = i;  // self loop first in each row
    int e = i - N;
    if (e >= 0 && e < E) col[row_ptr[dst[e]] + 1 + rank[e]] = src[e];
  }
}

// ---------------- standalone 32-row GEMM for layers 1,2 -----------------------------------------
// 32-row tiles double the wave count (~24/CU) vs 64-row; ~10KB LDS; identical fragment K-order.
__global__ __launch_bounds__(256) void k_gemm_fused32(const unsigned short* __restrict__ A16,
                                                      const _Float16* __restrict__ WtG,
                                                      unsigned short* __restrict__ hb,
                                                      const float* __restrict__ asrc,
                                                      const float* __restrict__ adst,
                                                      float* __restrict__ sv, float* __restrict__ dv,
                                                      unsigned* __restrict__ maxSlot, int M) {
  __shared__ __align__(16) _Float16 Ah[32 * AST];
  __shared__ float sred[4][32][2];
  int t = threadIdx.x;
  int rowbase = (int)blockIdx.x * 32;

  for (int i = t; i < 32 * 16; i += 256) {
    int r = i >> 4, c8 = (i & 15) << 3;
    int gr = rowbase + r;
    uint4 v = make_uint4(0u, 0u, 0u, 0u);
    if (gr < M) v = *(const uint4*)&A16[(size_t)gr * 128 + c8];
    *(uint4*)&Ah[r * AST + c8] = v;
  }
  __syncthreads();

  int wave = t >> 6, lane = t & 63, quad = lane >> 4, l15 = lane & 15;
  f32x4v acc[2][2];
#pragma unroll
  for (int mt = 0; mt < 2; mt++)
#pragma unroll
    for (int nt = 0; nt < 2; nt++) {
      acc[mt][nt][0] = 0.f; acc[mt][nt][1] = 0.f; acc[mt][nt][2] = 0.f; acc[mt][nt][3] = 0.f;
    }

#pragma unroll
  for (int s = 0; s < 4; s++) {
    int k0 = (s << 5) + (quad << 3);
    f16x8 af[2], bf[2];
#pragma unroll
    for (int mt = 0; mt < 2; mt++)
      af[mt] = *(f16x8*)&Ah[(mt * 16 + l15) * AST + k0];
#pragma unroll
    for (int nt = 0; nt < 2; nt++)
      bf[nt] = *(const f16x8*)&WtG[(size_t)(wave * 32 + nt * 16 + l15) * 128 + k0];
#pragma unroll
    for (int mt = 0; mt < 2; mt++)
#pragma unroll
      for (int nt = 0; nt < 2; nt++)
        acc[mt][nt] = __builtin_amdgcn_mfma_f32_16x16x32_f16(af[mt], bf[nt], acc[mt][nt], 0, 0, 0);
  }
  __syncthreads();

  float avv0 = asrc[wave * 32 + l15],      avv1 = asrc[wave * 32 + 16 + l15];
  float adv0 = adst[wave * 32 + l15],      adv1 = adst[wave * 32 + 16 + l15];
#pragma unroll
  for (int mt = 0; mt < 2; mt++) {
#pragma unroll
    for (int rr = 0; rr < 4; rr++) {
      int row = mt * 16 + quad * 4 + rr;
      Ah[row * AST + wave * 32 + l15]      = (_Float16)acc[mt][0][rr];
      Ah[row * AST + wave * 32 + 16 + l15] = (_Float16)acc[mt][1][rr];
      float ps = acc[mt][0][rr] * avv0 + acc[mt][1][rr] * avv1;
      float pd = acc[mt][0][rr] * adv0 + acc[mt][1][rr] * adv1;
#pragma unroll
      for (int mask = 8; mask; mask >>= 1) {
        ps += __shfl_xor(ps, mask);
        pd += __shfl_xor(pd, mask);
      }
      if (l15 == 0) { sred[wave][row][0] = ps; sred[wave][row][1] = pd; }
    }
  }
  __syncthreads();

  int tx = t & 31, ty = t >> 5;
#pragma unroll
  for (int r4 = 0; r4 < 4; r4++) {
    int row = r4 * 8 + ty;
    int gr = rowbase + row;
    if (gr < M)
      *(uint2*)&hb[(size_t)gr * 128 + tx * 4] = *(const uint2*)&Ah[row * AST + tx * 4];
  }

  if (t < 32) {
    int gr = rowbase + t;
    float ps = sred[0][t][0] + sred[1][t][0] + sred[2][t][0] + sred[3][t][0];
    float pd = sred[0][t][1] + sred[1][t][1] + sred[2][t][1] + sred[3][t][1];
    float wmax = -1e30f;
    if (gr < M) { sv[gr] = ps; dv[gr] = pd; wmax = ps; }
#pragma unroll
    for (int mask = 16; mask; mask >>= 1) wmax = fmaxf(wmax, __shfl_xor(wmax, mask));
    if (t == 0) atomicMax(&maxSlot[blockIdx.x & 255], enc_f(wmax));
  }
}

// ---------------- segment-softmax aggregation: 1 wave/node, phase-split, 4-deep rotation --------
// 48 VGPR, occ 44%, ~66us/layer. At the gather issue/latency + L2/L3-BW equilibrium
// (~6.4 TB/s effective on 423MB of logical gathers). Scheduling/VALU micro-opts exhausted:
// r6 (6-name unroll, +24 VGPR) -> 93us; r8 (4-name, zero-mov) -> neutral. Do not touch.
__global__ __launch_bounds__(256) void k_agg(const unsigned short* __restrict__ hb,
                                             const float* __restrict__ sv,
                                             const float* __restrict__ dv,
                                             const int* __restrict__ row_ptr,
                                             const int* __restrict__ col,
                                             const float* __restrict__ bias,
                                             const unsigned* __restrict__ maxSlot,
                                             unsigned short* __restrict__ out16,
                                             int N, int relu) {
  int wid = (int)((blockIdx.x * (size_t)blockDim.x + threadIdx.x) >> 6);
  int lane = threadIdx.x & 63;
  if (wid >= N) return;

  unsigned mp = max(max(maxSlot[lane], maxSlot[lane + 64]),
                    max(maxSlot[lane + 128], maxSlot[lane + 192]));
#pragma unroll
  for (int off = 32; off; off >>= 1) mp = max(mp, __shfl_xor(mp, off));
  float maxS = dec_f(mp);

  int beg = row_ptr[wid], end = row_ptr[wid + 1];
  float dn = dv[wid];
  float m = maxS + dn;
  m = (m > 0.f) ? m : NEG_SLOPE * m;  // upper bound on all incoming e (leaky_relu monotone)

  int g = lane >> 4, sub = lane & 15;
  const uint32_t* hbu = (const uint32_t*)hb;
  float acc[8];
#pragma unroll
  for (int k = 0; k < 8; k++) acc[k] = 0.f;
  float dsum = 0.f;

#define FETCH_SLOT(K, W, H)                                                \
  {                                                                        \
    int sl = ((K) << 2) + g;                                               \
    int sn = __shfl(sn_l, sl);                                             \
    W = __shfl(w_l, sl);                                                   \
    H = make_uint4(0u, 0u, 0u, 0u);                                        \
    if (sl < cnt) H = *(const uint4*)(hbu + (size_t)sn * 64 + sub * 4);    \
  }
#define ACC_SLOT(W, H)                                                     \
  {                                                                        \
    const _Float16* hp = (const _Float16*)&H;                              \
    _Pragma("unroll")                                                      \
    for (int q = 0; q < 8; q++) acc[q] += W * (float)hp[q];                \
  }

  for (int base = beg; base < end; base += 64) {
    int cnt = min(end - base, 64);

    // phase 1: vectorized edge prep across all 64 lanes
    int sn_l = 0;
    float w_l = 0.f;
    if (lane < cnt) {
      sn_l = col[base + lane];
      float e = sv[sn_l] + dn;
      e = (e > 0.f) ? e : NEG_SLOPE * e;
      w_l = __expf(e - m);
      dsum += w_l;
    }

    // phase 2: 4-deep rotation gather, no remainder (slots >= cnt contribute exactly 0)
    int kmaxW4 = (((cnt + 3) >> 2) + 3) & ~3;  // wave-uniform, 4..16
    float wA, wB, wC, wD;
    uint4 hA, hB, hC, hD;
    FETCH_SLOT(0, wA, hA);
    FETCH_SLOT(1, wB, hB);
    FETCH_SLOT(2, wC, hC);
    FETCH_SLOT(3, wD, hD);
    for (int k = 4; k < kmaxW4; k += 4) {
      ACC_SLOT(wA, hA); FETCH_SLOT(k + 0, wA, hA);
      ACC_SLOT(wB, hB); FETCH_SLOT(k + 1, wB, hB);
      ACC_SLOT(wC, hC); FETCH_SLOT(k + 2, wC, hC);
      ACC_SLOT(wD, hD); FETCH_SLOT(k + 3, wD, hD);
    }
    ACC_SLOT(wA, hA);
    ACC_SLOT(wB, hB);
    ACC_SLOT(wC, hC);
    ACC_SLOT(wD, hD);
  }

#pragma unroll
  for (int off = 1; off < 64; off <<= 1) dsum += __shfl_xor(dsum, off);
#pragma unroll
  for (int k = 0; k < 8; k++) {
    acc[k] += __shfl_xor(acc[k], 16);
    acc[k] += __shfl_xor(acc[k], 32);
  }
  if (lane < 16) {
    float inv = 1.f / dsum;
    float o[8];
    const float* bp = &bias[sub * 8];
#pragma unroll
    for (int k = 0; k < 8; k++) {
      o[k] = acc[k] * inv + bp[k];
      if (relu) o[k] = fmaxf(o[k], 0.f);
    }
    _Float16 q[8];
#pragma unroll
    for (int k = 0; k < 8; k++) q[k] = (_Float16)o[k];
    *(uint4*)&out16[(size_t)wid * 128 + sub * 8] = *(uint4*)q;
  }
}

// ---------------- mean pool + relu -> fp16, one block per graph ----------------
// Do NOT fuse with the MLP (r4: B/4 grid + serialized graphs -> 5.6% occ, 95us).
__global__ __launch_bounds__(256) void k_pool(const unsigned short* __restrict__ h16,
                                              const int* __restrict__ gstart,
                                              unsigned short* __restrict__ pooled16, int B) {
  __shared__ float red[4][128];
  int b = blockIdx.x, t = threadIdx.x;
  int c = t & 63, seg = t >> 6;
  int s0 = gstart[b], s1 = gstart[b + 1];
  int cnt = s1 - s0;
  int per = (cnt + 3) >> 2;
  int n0 = s0 + seg * per;
  int n1 = min(n0 + per, s1);
  const uint32_t* hu = (const uint32_t*)h16;
  float a0 = 0.f, a1 = 0.f;
  for (int n = n0; n < n1; n++) {
    union { uint32_t u; _Float16 h[2]; } cv;
    cv.u = hu[(size_t)n * 64 + c];
    a0 += (float)cv.h[0];
    a1 += (float)cv.h[1];
  }
  if (seg) { red[seg][2 * c] = a0; red[seg][2 * c + 1] = a1; }
  __syncthreads();
  if (seg == 0) {
    a0 += red[1][2 * c] + red[2][2 * c] + red[3][2 * c];
    a1 += red[1][2 * c + 1] + red[2][2 * c + 1] + red[3][2 * c + 1];
    float inv = 1.f / (float)(cnt > 0 ? cnt : 1);
    union { uint32_t u; _Float16 h[2]; } ov;
    ov.h[0] = (_Float16)fmaxf(a0 * inv, 0.f);
    ov.h[1] = (_Float16)fmaxf(a1 * inv, 0.f);
    *(uint32_t*)&pooled16[(size_t)b * 128 + 2 * c] = ov.u;
  }
}

// ---------------- MFMA MLP layer 1: H1 = relu(P @ Wf1 + bf1), fp16 out ----------------
__global__ __launch_bounds__(256) void k_mlp1(const unsigned short* __restrict__ P16,
                                              const _Float16* __restrict__ Wf1t,
                                              const float* __restrict__ bf1,
                                              unsigned short* __restrict__ H1g, int B, int nRow) {
  __shared__ __align__(16) _Float16 Ah[64 * AST];
  int bx = (int)blockIdx.x;
  int rowt = bx % nRow, colt = bx / nRow;
  int rowbase = rowt * 64;
  int t = threadIdx.x;

  for (int i = t; i < 64 * 16; i += 256) {
    int r = i >> 4, c8 = (i & 15) << 3;
    int gr = rowbase + r;
    uint4 v = make_uint4(0u, 0u, 0u, 0u);
    if (gr < B) v = *(const uint4*)&P16[(size_t)gr * 128 + c8];
    *(uint4*)&Ah[r * AST + c8] = v;
  }
  __syncthreads();

  int wave = t >> 6, lane = t & 63, quad = lane >> 4, l15 = lane & 15;
  int colbase = colt * 128 + wave * 32;
  f32x4v acc[4][2];
#pragma unroll
  for (int mt = 0; mt < 4; mt++)
#pragma unroll
    for (int nt = 0; nt < 2; nt++) {
      acc[mt][nt][0] = 0.f; acc[mt][nt][1] = 0.f; acc[mt][nt][2] = 0.f; acc[mt][nt][3] = 0.f;
    }
#pragma unroll
  for (int s = 0; s < 4; s++) {
    int k0 = (s << 5) + (quad << 3);
    f16x8 af[4], bf[2];
#pragma unroll
    for (int mt = 0; mt < 4; mt++)
      af[mt] = *(f16x8*)&Ah[(mt * 16 + l15) * AST + k0];
#pragma unroll
    for (int nt = 0; nt < 2; nt++)
      bf[nt] = *(const f16x8*)&Wf1t[(size_t)(colbase + nt * 16 + l15) * 128 + k0];
#pragma unroll
    for (int mt = 0; mt < 4; mt++)
#pragma unroll
      for (int nt = 0; nt < 2; nt++)
        acc[mt][nt] = __builtin_amdgcn_mfma_f32_16x16x32_f16(af[mt], bf[nt], acc[mt][nt], 0, 0, 0);
  }

  float b0 = bf1[colbase + l15], b1 = bf1[colbase + 16 + l15];
#pragma unroll
  for (int mt = 0; mt < 4; mt++)
#pragma unroll
    for (int rr = 0; rr < 4; rr++) {
      int gr = rowbase + mt * 16 + quad * 4 + rr;
      if (gr < B) {
        H1g[(size_t)gr * 1024 + colbase + l15] =
            (unsigned short)__builtin_bit_cast(unsigned short, (_Float16)fmaxf(acc[mt][0][rr] + b0, 0.f));
        H1g[(size_t)gr * 1024 + colbase + 16 + l15] =
            (unsigned short)__builtin_bit_cast(unsigned short, (_Float16)fmaxf(acc[mt][1][rr] + b1, 0.f));
      }
    }
}

// ---------------- MFMA MLP layer 2: out = H1 @ Wf2 + bf2 (f32) ----------------
__global__ __launch_bounds__(256) void k_mlp2(const unsigned short* __restrict__ H1g,
                                              const _Float16* __restrict__ Wf2t,
                                              const float* __restrict__ bf2,
                                              float* __restrict__ out, int B) {
  __shared__ __align__(16) _Float16 Ah[64 * AST];
  int rowbase = (int)blockIdx.x * 64;
  int t = threadIdx.x;
  int wave = t >> 6, lane = t & 63, quad = lane >> 4, l15 = lane & 15;

  f32x4v acc[4][2];
#pragma unroll
  for (int mt = 0; mt < 4; mt++)
#pragma unroll
    for (int nt = 0; nt < 2; nt++) {
      acc[mt][nt][0] = 0.f; acc[mt][nt][1] = 0.f; acc[mt][nt][2] = 0.f; acc[mt][nt][3] = 0.f;
    }

  for (int kc = 0; kc < 8; kc++) {
    for (int i = t; i < 64 * 16; i += 256) {
      int r = i >> 4, c8 = (i & 15) << 3;
      int gr = rowbase + r;
      uint4 v = make_uint4(0u, 0u, 0u, 0u);
      if (gr < B) v = *(const uint4*)&H1g[(size_t)gr * 1024 + kc * 128 + c8];
      *(uint4*)&Ah[r * AST + c8] = v;
    }
    __syncthreads();
#pragma unroll
    for (int s = 0; s < 4; s++) {
      int k0 = (s << 5) + (quad << 3);
      f16x8 af[4], bf[2];
#pragma unroll
      for (int mt = 0; mt < 4; mt++)
        af[mt] = *(f16x8*)&Ah[(mt * 16 + l15) * AST + k0];
#pragma unroll
      for (int nt = 0; nt < 2; nt++)
        bf[nt] = *(const f16x8*)&Wf2t[(size_t)(wave * 32 + nt * 16 + l15) * 1024 + kc * 128 + k0];
#pragma unroll
      for (int mt = 0; mt < 4; mt++)
#pragma unroll
        for (int nt = 0; nt < 2; nt++)
          acc[mt][nt] = __builtin_amdgcn_mfma_f32_16x16x32_f16(af[mt], bf[nt], acc[mt][nt], 0, 0, 0);
    }
    __syncthreads();
  }

  int col0 = wave * 32 + l15, col1 = col0 + 16;
  float b0 = bf2[col0], b1 = bf2[col1];
#pragma unroll
  for (int mt = 0; mt < 4; mt++)
#pragma unroll
    for (int rr = 0; rr < 4; rr++) {
      int gr = rowbase + mt * 16 + quad * 4 + rr;
      if (gr < B) {
        out[(size_t)gr * 128 + col0] = acc[mt][0][rr] + b0;
        out[(size_t)gr * 128 + col1] = acc[mt][1][rr] + b1;
      }
    }
}

extern "C" void kernel_launch(void* const* d_in, const int* in_sizes, int n_in,
                              void* d_out, int out_size, void* d_ws, size_t ws_size,
                              hipStream_t stream) {
  const float* x     = (const float*)d_in[0];
  const int*   ei    = (const int*)d_in[1];
  const int*   batch = (const int*)d_in[3];
  const float* W1 = (const float*)d_in[4];
  const float* as1 = (const float*)d_in[5];
  const float* ad1 = (const float*)d_in[6];
  const float* b1 = (const float*)d_in[7];
  const float* W2 = (const float*)d_in[8];
  const float* as2 = (const float*)d_in[9];
  const float* ad2 = (const float*)d_in[10];
  const float* b2 = (const float*)d_in[11];
  const float* W3 = (const float*)d_in[12];
  const float* as3 = (const float*)d_in[13];
  const float* ad3 = (const float*)d_in[14];
  const float* b3 = (const float*)d_in[15];
  const float* Wf1 = (const float*)d_in[16];
  const float* bf1 = (const float*)d_in[17];
  const float* Wf2 = (const float*)d_in[18];
  const float* bf2 = (const float*)d_in[19];

  const int N = in_sizes[0] / 128;
  const int E = in_sizes[1] / 2;
  const int B = out_size / 128;

  char* base_ws = (char*)d_ws;
  size_t off = 0;
  auto carve = [&](size_t bytes) -> void* {
    off = (off + 255) & ~(size_t)255;
    void* p = base_ws + off;
    off += bytes;
    return p;
  };
  int* counts   = (int*)carve((size_t)N * 4);
  int* row_ptr  = (int*)carve((size_t)(N + 1) * 4);
  int* rank     = (int*)carve((size_t)E * 4);
  int* col      = (int*)carve((size_t)(E + N) * 4);
  int* part     = (int*)carve(1024 * 4);
  int* gstart   = (int*)carve((size_t)(B + 1) * 4);
  unsigned* maxPart = (unsigned*)carve(768 * 4);
  float* sbuf   = (float*)carve((size_t)N * 4);
  float* dbuf   = (float*)carve((size_t)N * 4);
  unsigned short* hb  = (unsigned short*)carve((size_t)N * 128 * 2);
  unsigned short* a16 = (unsigned short*)carve((size_t)N * 128 * 2);
  unsigned short* pooled16 = (unsigned short*)carve((size_t)B * 128 * 2);
  unsigned short* H1g = (unsigned short*)carve((size_t)B * 1024 * 2);
  _Float16* Wt1 = (_Float16*)carve(128 * 128 * 2);
  _Float16* Wt2 = (_Float16*)carve(128 * 128 * 2);
  _Float16* Wt3 = (_Float16*)carve(128 * 128 * 2);
  _Float16* Wf1t = (_Float16*)carve((size_t)1024 * 128 * 2);
  _Float16* Wf2t = (_Float16*)carve((size_t)128 * 1024 * 2);

  const int* srcp = ei;
  const int* dstp = ei + E;
  const int nb = (N + 1023) / 1024;
  const int Gg = (N + 63) / 64;                 // 64-row gemm tiles (layer 0, under fill)
  const int Gg2 = (N + 31) / 32;                // 32-row gemm tiles (layers 1,2)
  const int Gf = (E + N + 255) / 256;           // fill blocks
  const int nbb = (N + 255) / 256;              // bounds blocks
  const int Cb = (E + 255) / 256;               // count blocks
  const int nRow = (B + 63) / 64;               // mlp row tiles

  hipMemsetAsync(counts, 0, (size_t)N * 4, stream);
  // prep (bounds + W transposes, blocks first) || count_rank — all LDS-free
  hipLaunchKernelGGL(k_count_prep, dim3(nbb + 19 + Cb), dim3(256), 0, stream,
                     dstp, E, counts, rank,
                     batch, N, B, gstart, maxPart,
                     W1, W2, W3, Wf1, Wf2, Wt1, Wt2, Wt3, Wf1t, Wf2t, nbb);
  hipLaunchKernelGGL(k_scan1, dim3(nb), dim3(1024), 0, stream, counts, N, row_ptr, part);
  hipLaunchKernelGGL(k_scan3, dim3(nb), dim3(1024), 0, stream, row_ptr, part, N);

  // fill (CSR scatter) || gemm layer 0 — independent, interleaved in one grid
  hipLaunchKernelGGL(k_fill_gemm, dim3(Gf + Gg), dim3(256), 0, stream,
                     srcp, dstp, rank, E, N, row_ptr, col,
                     x, Wt1, hb, as1, ad1, sbuf, dbuf, maxPart + 0 * 256, Gg);

  hipLaunchKernelGGL(k_agg, dim3((N + 3) / 4), dim3(256), 0, stream,
                     hb, sbuf, dbuf, row_ptr, col, b1, maxPart + 0 * 256, a16, N, 0);

  hipLaunchKernelGGL(k_gemm_fused32, dim3(Gg2), dim3(256), 0, stream,
                     a16, Wt2, hb, as2, ad2, sbuf, dbuf, maxPart + 1 * 256, N);
  hipLaunchKernelGGL(k_agg, dim3((N + 3) / 4), dim3(256), 0, stream,
                     hb, sbuf, dbuf, row_ptr, col, b2, maxPart + 1 * 256, a16, N, 1);

  hipLaunchKernelGGL(k_gemm_fused32, dim3(Gg2), dim3(256), 0, stream,
                     a16, Wt3, hb, as3, ad3, sbuf, dbuf, maxPart + 2 * 256, N);
  hipLaunchKernelGGL(k_agg, dim3((N + 3) / 4), dim3(256), 0, stream,
                     hb, sbuf, dbuf, row_ptr, col, b3, maxPart + 2 * 256, a16, N, 1);

  hipLaunchKernelGGL(k_pool, dim3(B), dim3(256), 0, stream, a16, gstart, pooled16, B);
  hipLaunchKernelGGL(k_mlp1, dim3(nRow * 8), dim3(256), 0, stream,
                     pooled16, Wf1t, bf1, H1g, B, nRow);
  hipLaunchKernelGGL(k_mlp2, dim3(nRow), dim3(256), 0, stream,
                     H1g, Wf2t, bf2, (float*)d_out, B);
}